// Round 6
// baseline (584.250 us; speedup 1.0000x reference)
//
#include <hip/hip_runtime.h>
#include <math.h>

#define L_SEQ 1024
#define M_ROWS 2048
#define PI_F 3.14159265358979323846f
#define NBLK 256

typedef short bf16x8 __attribute__((ext_vector_type(8)));
typedef float f32x4 __attribute__((ext_vector_type(4)));

__device__ __forceinline__ unsigned short bf16_rne(float x) {
    union { float f; unsigned u; } v; v.f = x;
    unsigned r = v.u + 0x7fffu + ((v.u >> 16) & 1u);
    return (unsigned short)(r >> 16);
}
__device__ __forceinline__ float bf16_tof(unsigned short h) {
    union { unsigned u; float f; } v; v.u = ((unsigned)h) << 16;
    return v.f;
}
__device__ __forceinline__ void split2(float x, unsigned short &h, unsigned short &l) {
    h = bf16_rne(x);
    l = bf16_rne(x - bf16_tof(h));
}
__device__ __forceinline__ float gelu_exact(float x) {
    return 0.5f * x * (1.0f + erff(x * 0.70710678118654752f));
}
__device__ __forceinline__ f32x4 mfma16(bf16x8 a, bf16x8 b, f32x4 c) {
    return __builtin_amdgcn_mfma_f32_16x16x32_bf16(a, b, c, 0, 0, 0);
}
__device__ __forceinline__ void gload_lds16(const unsigned short* g, unsigned short* l) {
    __builtin_amdgcn_global_load_lds(
        (const __attribute__((address_space(1))) void*)g,
        (__attribute__((address_space(3))) void*)l, 16, 0, 0);
}

// Stage one [R rows x 32 k] bf16 tile into LDS (row = 64B), pre-swizzled src.
__device__ __forceinline__ void stage_tile(
    const unsigned short* __restrict__ src, int ld, int rowBase, int k0,
    unsigned short* lds_tile, int R)
{
    const int tid = threadIdx.x;
    for (int i = 0; i < (R >> 6); ++i) {
        const int r = i * 64 + (tid >> 2);
        const int c = (tid & 3) ^ ((r >> 1) & 3);
        const unsigned short* g = src + (size_t)(rowBase + r) * ld + k0 + c * 8;
        unsigned short* l = lds_tile + i * 2048 + (tid & 192) * 8;  // wave-uniform
        gload_lds16(g, l);
    }
}

// LDS-staged split-bf16 GEMM core. 256 threads = 4 waves (2x2).
// Block tile = (MI*32) x (NI*32). A/B: [rows][k] row-major, k-contiguous.
template<int MI, int NI>
__device__ __forceinline__ void lds_gemm(
    unsigned short* lds,
    const unsigned short* Ah_, const unsigned short* Al_, int lda, int aRow,
    const unsigned short* Bh_, const unsigned short* Bl_, int ldb, int bRow,
    int k0, int nk, f32x4 (&acc)[MI][NI])
{
    constexpr int SZA = MI * 32 * 32;
    constexpr int SZB = NI * 32 * 32;
    constexpr int BUF = 2 * SZA + 2 * SZB;
    const int tid = threadIdx.x, lane = tid & 63;
    const int wm = (tid >> 7) & 1, wn = (tid >> 6) & 1;

    stage_tile(Ah_, lda, aRow, k0, lds,                 MI * 32);
    stage_tile(Al_, lda, aRow, k0, lds + SZA,           MI * 32);
    stage_tile(Bh_, ldb, bRow, k0, lds + 2 * SZA,       NI * 32);
    stage_tile(Bl_, ldb, bRow, k0, lds + 2 * SZA + SZB, NI * 32);

    for (int ks = 0; ks < nk; ++ks) {
        const int cur = (ks & 1) * BUF;
        const int nxt = ((ks & 1) ^ 1) * BUF;
        __syncthreads();
        if (ks + 1 < nk) {
            const int kk = k0 + (ks + 1) * 32;
            stage_tile(Ah_, lda, aRow, kk, lds + nxt,                 MI * 32);
            stage_tile(Al_, lda, aRow, kk, lds + nxt + SZA,           MI * 32);
            stage_tile(Bh_, ldb, bRow, kk, lds + nxt + 2 * SZA,       NI * 32);
            stage_tile(Bl_, ldb, bRow, kk, lds + nxt + 2 * SZA + SZB, NI * 32);
        }
        const int lr = lane & 15, j = lane >> 4;
        bf16x8 ah[MI], al[MI], bh[NI], bl[NI];
#pragma unroll
        for (int mi = 0; mi < MI; ++mi) {
            const int r = wm * (MI * 16) + mi * 16 + lr;
            const int off = cur + r * 32 + ((j ^ ((r >> 1) & 3)) << 3);
            ah[mi] = *(const bf16x8*)(lds + off);
            al[mi] = *(const bf16x8*)(lds + off + SZA);
        }
#pragma unroll
        for (int ni = 0; ni < NI; ++ni) {
            const int r = wn * (NI * 16) + ni * 16 + lr;
            const int off = cur + 2 * SZA + r * 32 + ((j ^ ((r >> 1) & 3)) << 3);
            bh[ni] = *(const bf16x8*)(lds + off);
            bl[ni] = *(const bf16x8*)(lds + off + SZB);
        }
#pragma unroll
        for (int mi = 0; mi < MI; ++mi)
#pragma unroll
            for (int ni = 0; ni < NI; ++ni) {
                acc[mi][ni] = mfma16(ah[mi], bh[ni], acc[mi][ni]);
                acc[mi][ni] = mfma16(ah[mi], bl[ni], acc[mi][ni]);
                acc[mi][ni] = mfma16(al[mi], bh[ni], acc[mi][ni]);
            }
    }
}

// Device-scope grid barrier. Safe: 256 blocks, 64KB LDS -> all co-resident.
// bars[2i]=counter, bars[2i+1]=flag; zeroed by hipMemsetAsync pre-launch.
__device__ __forceinline__ void grid_barrier(unsigned* bars, int id) {
    __syncthreads();
    if (threadIdx.x == 0) {
        __threadfence();   // release: wb dirty L2 to coherence point (cross-XCD)
        unsigned old = __hip_atomic_fetch_add(&bars[id * 2], 1u,
                          __ATOMIC_ACQ_REL, __HIP_MEMORY_SCOPE_AGENT);
        if (old == NBLK - 1) {
            __hip_atomic_store(&bars[id * 2 + 1], 1u,
                          __ATOMIC_RELEASE, __HIP_MEMORY_SCOPE_AGENT);
        } else {
            while (!__hip_atomic_load(&bars[id * 2 + 1],
                          __ATOMIC_ACQUIRE, __HIP_MEMORY_SCOPE_AGENT))
                __builtin_amdgcn_s_sleep(2);
        }
        __threadfence();   // acquire: invalidate stale L1/L2 lines
    }
    __syncthreads();
}

// ---------------------------------------------------------------------------
// One persistent kernel: prep | qkv | phase | scores | av | ln | out
// ---------------------------------------------------------------------------
__global__ __launch_bounds__(256) void mega(
    const float* x,
    const float* Wk1, const float* bk1, const float* Wk2, const float* bk2,
    const float* Wq1, const float* bq1, const float* Wq2, const float* bq2,
    const float* Wv,  const float* bv,
    const float* lng, const float* lnb,
    const float* Wo,  const float* bo,
    float* out,
    unsigned short* Wt_h, unsigned short* Wt_l,
    unsigned short* XYh,  unsigned short* XYl,   // X (phase B) then Y (phase F+)
    unsigned short* Hk_h, unsigned short* Hk_l,
    unsigned short* Hq_h, unsigned short* Hq_l,
    unsigned short* Vt_h, unsigned short* Vt_l,
    unsigned short* CSk_h, unsigned short* CSk_l,
    unsigned short* CSq_h, unsigned short* CSq_l,
    unsigned short* Ah, unsigned short* Al,
    float* Rp,
    unsigned* bars)
{
    __shared__ __align__(16) unsigned short lds[32768];   // 64KB, reused per phase
    const int bid = blockIdx.x;
    const int tid = threadIdx.x;
    const int lane = tid & 63, wid = tid >> 6;

    // ---------------- Phase A: prep (W transpose+split, X split) ------------
    for (int u = bid; u < 272; u += NBLK) {
        const int kT = u & 7, ty = u >> 3;
        const float* src; int srcN, dstRowBase, nBase;
        if (ty < 8)       { src = Wk1; srcN = 512; dstRowBase = 0;    nBase = ty * 64; }
        else if (ty < 16) { src = Wq1; srcN = 512; dstRowBase = 512;  nBase = (ty-8)*64; }
        else if (ty < 24) { src = Wv;  srcN = 512; dstRowBase = 1024; nBase = (ty-16)*64; }
        else if (ty < 32) { src = Wo;  srcN = 512; dstRowBase = 1536; nBase = (ty-24)*64; }
        else if (ty == 32){ src = Wk2; srcN = 64;  dstRowBase = 2048; nBase = 0; }
        else              { src = Wq2; srcN = 64;  dstRowBase = 2112; nBase = 0; }
        float* T = (float*)lds;   // [64][65]
        const int k0 = kT * 64;
        {
            const int r = tid >> 2, c0 = (tid & 3) * 16;
#pragma unroll
            for (int i = 0; i < 4; ++i) {
                float4 v = *reinterpret_cast<const float4*>(
                    src + (size_t)(k0 + r) * srcN + nBase + c0 + i*4);
                T[r*65 + c0+i*4+0] = v.x; T[r*65 + c0+i*4+1] = v.y;
                T[r*65 + c0+i*4+2] = v.z; T[r*65 + c0+i*4+3] = v.w;
            }
        }
        __syncthreads();
        {
            const int n = tid >> 2, kk0 = (tid & 3) * 16;
            const size_t base = (size_t)(dstRowBase + nBase + n) * 512 + k0 + kk0;
#pragma unroll
            for (int i = 0; i < 16; ++i) {
                unsigned short h, l;
                split2(T[(kk0 + i)*65 + n], h, l);
                Wt_h[base + i] = h; Wt_l[base + i] = l;
            }
        }
        __syncthreads();
    }
    {   // X split: 262144 float4 over 256 blocks
#pragma unroll
        for (int ii = 0; ii < 4; ++ii) {
            const size_t i = (size_t)bid * 1024 + ii * 256 + tid;
            float4 v = reinterpret_cast<const float4*>(x)[i];
            unsigned short h0,h1,h2,h3,l0,l1,l2,l3;
            split2(v.x,h0,l0); split2(v.y,h1,l1); split2(v.z,h2,l2); split2(v.w,h3,l3);
            unsigned long long hp = (unsigned long long)h0 | ((unsigned long long)h1<<16)
                                  | ((unsigned long long)h2<<32) | ((unsigned long long)h3<<48);
            unsigned long long lp = (unsigned long long)l0 | ((unsigned long long)l1<<16)
                                  | ((unsigned long long)l2<<32) | ((unsigned long long)l3<<48);
            reinterpret_cast<unsigned long long*>(XYh)[i] = hp;
            reinterpret_cast<unsigned long long*>(XYl)[i] = lp;
        }
    }
    grid_barrier(bars, 0);

    // ---------------- Phase B: fused QKV (192 tiles of 128x128) -------------
    if (bid < 192) {
        const int nT = bid % 12, mT = bid / 12;
        const int mBase = mT * 128, nBase = nT * 128;
        const int wm = (tid >> 7) & 1, wn = (tid >> 6) & 1;
        f32x4 acc[4][4];
#pragma unroll
        for (int i = 0; i < 4; ++i)
#pragma unroll
            for (int jj = 0; jj < 4; ++jj) acc[i][jj] = (f32x4){0.f,0.f,0.f,0.f};
        lds_gemm<4,4>(lds, XYh, XYl, 512, mBase, Wt_h, Wt_l, 512, nBase, 0, 16, acc);
        const int seg = nBase >> 9;
        const float* bias = (seg == 0) ? bk1 : (seg == 1) ? bq1 : bv;
#pragma unroll
        for (int mi = 0; mi < 4; ++mi)
#pragma unroll
        for (int ni = 0; ni < 4; ++ni)
#pragma unroll
        for (int r = 0; r < 4; ++r) {
            const int row = mBase + wm*64 + mi*16 + (lane>>4)*4 + r;
            const int col = nBase + wn*64 + ni*16 + (lane&15);
            const int nW = col & 511;
            float v = acc[mi][ni][r] + bias[nW];
            if (seg < 2) v = gelu_exact(v);
            unsigned short h, l;
            split2(v, h, l);
            if (seg == 0)      { Hk_h[(size_t)row*512 + nW] = h; Hk_l[(size_t)row*512 + nW] = l; }
            else if (seg == 1) { Hq_h[(size_t)row*512 + nW] = h; Hq_l[(size_t)row*512 + nW] = l; }
            else {
                const size_t o = (size_t)((row >> 10)*512 + nW) * 1024 + (row & 1023);
                Vt_h[o] = h; Vt_l[o] = l;
            }
        }
    }
    grid_barrier(bars, 1);

    // ---------------- Phase C: phase heads (64 tiles of 64x64) --------------
    if (bid < 64) {
        const int enc = bid & 1, mT = bid >> 1;
        const unsigned short* Ah_ = enc ? Hq_h : Hk_h;
        const unsigned short* Al_ = enc ? Hq_l : Hk_l;
        const float* b2 = enc ? bq2 : bk2;
        unsigned short* Ch = enc ? CSq_h : CSk_h;
        unsigned short* Cl = enc ? CSq_l : CSk_l;
        const int wm = (tid >> 7) & 1, wn = (tid >> 6) & 1;
        f32x4 acc[2][2];
#pragma unroll
        for (int i = 0; i < 2; ++i)
#pragma unroll
            for (int jj = 0; jj < 2; ++jj) acc[i][jj] = (f32x4){0.f,0.f,0.f,0.f};
        lds_gemm<2,2>(lds, Ah_, Al_, 512, mT*64, Wt_h, Wt_l, 512, 2048 + enc*64, 0, 16, acc);
#pragma unroll
        for (int mi = 0; mi < 2; ++mi)
#pragma unroll
        for (int ni = 0; ni < 2; ++ni)
#pragma unroll
        for (int r = 0; r < 4; ++r) {
            const int row = mT*64 + wm*32 + mi*16 + (lane>>4)*4 + r;
            const int j = wn*32 + ni*16 + (lane&15);
            float p = acc[mi][ni][r] + b2[j];
            p = tanhf(p) * PI_F;
            float s, c;
            sincosf(p, &s, &c);
            unsigned short h, l;
            split2(c, h, l);
            Ch[(size_t)row*128 + j] = h; Cl[(size_t)row*128 + j] = l;
            split2(s, h, l);
            Ch[(size_t)row*128 + 64 + j] = h; Cl[(size_t)row*128 + 64 + j] = l;
        }
    }
    grid_barrier(bars, 2);

    // ---------------- Phase D: scores (lower-tri 128x128 tiles) -------------
    if (bid < 128) {
        const int sT = bid & 7, tT = (bid >> 3) & 7, b = bid >> 6;
        if (sT <= tT) {
            const int wm = (tid >> 7) & 1, wn = (tid >> 6) & 1;
            f32x4 acc[4][4];
#pragma unroll
            for (int i = 0; i < 4; ++i)
#pragma unroll
                for (int jj = 0; jj < 4; ++jj) acc[i][jj] = (f32x4){0.f,0.f,0.f,0.f};
            lds_gemm<4,4>(lds, CSq_h, CSq_l, 128, b*1024 + tT*128,
                          CSk_h, CSk_l, 128, b*1024 + sT*128, 0, 4, acc);
#pragma unroll
            for (int mi = 0; mi < 4; ++mi)
#pragma unroll
            for (int ni = 0; ni < 4; ++ni)
#pragma unroll
            for (int r = 0; r < 4; ++r) {
                const int t = tT*128 + wm*64 + mi*16 + (lane>>4)*4 + r;
                const int s = sT*128 + wn*64 + ni*16 + (lane&15);
                float v = (s <= t) ? acc[mi][ni][r] : 0.f;
                unsigned short h, l;
                split2(v, h, l);
                const size_t o = ((size_t)b*1024 + t) * 1024 + s;
                Ah[o] = h; Al[o] = l;
            }
        }
    }
    grid_barrier(bars, 3);

    // ---------------- Phase E: causal AV (s-chunked partials) ---------------
    {
        const int dT = bid & 3, tT = (bid >> 2) & 7, b = (bid >> 5) & 1, c = bid >> 6;
        if (c <= (tT >> 1)) {
            const int wm = (tid >> 7) & 1, wn = (tid >> 6) & 1;
            const int kLen = min(256, tT*128 + 128 - c*256);
            const int nk = kLen >> 5;
            f32x4 acc[4][4];
#pragma unroll
            for (int i = 0; i < 4; ++i)
#pragma unroll
                for (int jj = 0; jj < 4; ++jj) acc[i][jj] = (f32x4){0.f,0.f,0.f,0.f};
            lds_gemm<4,4>(lds, Ah, Al, 1024, b*1024 + tT*128,
                          Vt_h, Vt_l, 1024, b*512 + dT*128, c*256, nk, acc);
            float* Rb = Rp + (size_t)c * (M_ROWS * 512);
#pragma unroll
            for (int mi = 0; mi < 4; ++mi)
#pragma unroll
            for (int ni = 0; ni < 4; ++ni)
#pragma unroll
            for (int r = 0; r < 4; ++r) {
                const int row = b*1024 + tT*128 + wm*64 + mi*16 + (lane>>4)*4 + r;
                const int d = dT*128 + wn*64 + ni*16 + (lane&15);
                Rb[(size_t)row*512 + d] = acc[mi][ni][r];
            }
        }
    }
    grid_barrier(bars, 4);

    // ---------------- Phase F: LayerNorm -> Y (bf16 split, into XY*) --------
    {
        float* fbuf = (float*)lds;
        for (int i = 0; i < 8; ++i) {
            const int row = bid * 8 + i;
            const int t = row & (L_SEQ - 1);
            const int nc = (t >> 8) + 1;
            const float scale = rsqrtf((float)(t + 1) * 64.0f);
            float v0 = 0.f, v1 = 0.f;
            for (int c = 0; c < nc; ++c) {
                const float* Rr = Rp + (size_t)c * (M_ROWS * 512) + (size_t)row * 512;
                v0 += Rr[tid];
                v1 += Rr[256 + tid];
            }
            v0 *= scale; v1 *= scale;
            float s = v0 + v1, q = v0*v0 + v1*v1;
#pragma unroll
            for (int off = 32; off >= 1; off >>= 1) {
                s += __shfl_down(s, off);
                q += __shfl_down(q, off);
            }
            if (lane == 0) { fbuf[wid] = s; fbuf[4 + wid] = q; }
            __syncthreads();
            const float S = fbuf[0] + fbuf[1] + fbuf[2] + fbuf[3];
            const float Q = fbuf[4] + fbuf[5] + fbuf[6] + fbuf[7];
            const float mu  = S * (1.f / 512.f);
            const float var = Q * (1.f / 512.f) - mu * mu;
            const float rr = rsqrtf(var + 1e-5f);
            const float y0 = (v0 - mu) * rr * lng[tid]       + lnb[tid];
            const float y1 = (v1 - mu) * rr * lng[256 + tid] + lnb[256 + tid];
            unsigned short h, l;
            split2(y0, h, l);
            XYh[(size_t)row*512 + tid] = h;       XYl[(size_t)row*512 + tid] = l;
            split2(y1, h, l);
            XYh[(size_t)row*512 + 256 + tid] = h; XYl[(size_t)row*512 + 256 + tid] = l;
            __syncthreads();
        }
    }
    grid_barrier(bars, 5);

    // ---------------- Phase G: out = x + Y @ Wo + bo (256 tiles 64x64) ------
    {
        const int nT = bid & 7, mT = bid >> 3;
        const int wm = (tid >> 7) & 1, wn = (tid >> 6) & 1;
        f32x4 acc[2][2];
#pragma unroll
        for (int i = 0; i < 2; ++i)
#pragma unroll
            for (int jj = 0; jj < 2; ++jj) acc[i][jj] = (f32x4){0.f,0.f,0.f,0.f};
        lds_gemm<2,2>(lds, XYh, XYl, 512, mT*64, Wt_h, Wt_l, 512, 1536 + nT*64, 0, 16, acc);
#pragma unroll
        for (int mi = 0; mi < 2; ++mi)
#pragma unroll
        for (int ni = 0; ni < 2; ++ni)
#pragma unroll
        for (int r = 0; r < 4; ++r) {
            const int row = mT*64 + wm*32 + mi*16 + (lane>>4)*4 + r;
            const int col = nT*64 + wn*32 + ni*16 + (lane&15);
            out[(size_t)row*512 + col] =
                acc[mi][ni][r] + bo[col] + x[(size_t)row*512 + col];
        }
    }
}

// ---------------------------------------------------------------------------
extern "C" void kernel_launch(void* const* d_in, const int* in_sizes, int n_in,
                              void* d_out, int out_size, void* d_ws, size_t ws_size,
                              hipStream_t stream)
{
    const float* x   = (const float*)d_in[0];
    const float* Wk1 = (const float*)d_in[1];
    const float* bk1 = (const float*)d_in[2];
    const float* Wk2 = (const float*)d_in[3];
    const float* bk2 = (const float*)d_in[4];
    const float* Wq1 = (const float*)d_in[5];
    const float* bq1 = (const float*)d_in[6];
    const float* Wq2 = (const float*)d_in[7];
    const float* bq2 = (const float*)d_in[8];
    const float* Wv  = (const float*)d_in[9];
    const float* bv  = (const float*)d_in[10];
    const float* lng = (const float*)d_in[11];
    const float* lnb = (const float*)d_in[12];
    const float* Wo  = (const float*)d_in[13];
    const float* bo  = (const float*)d_in[14];
    float* out = (float*)d_out;

    unsigned short* us = (unsigned short*)d_ws;
    size_t o = 0;
    unsigned short* Wt_h  = us + o; o += (size_t)2176*512;
    unsigned short* Wt_l  = us + o; o += (size_t)2176*512;
    unsigned short* XYh   = us + o; o += (size_t)2048*512;
    unsigned short* XYl   = us + o; o += (size_t)2048*512;
    unsigned short* Hk_h  = us + o; o += (size_t)2048*512;
    unsigned short* Hk_l  = us + o; o += (size_t)2048*512;
    unsigned short* Hq_h  = us + o; o += (size_t)2048*512;
    unsigned short* Hq_l  = us + o; o += (size_t)2048*512;
    unsigned short* Vt_h  = us + o; o += (size_t)2*512*1024;
    unsigned short* Vt_l  = us + o; o += (size_t)2*512*1024;
    unsigned short* CSk_h = us + o; o += (size_t)2048*128;
    unsigned short* CSk_l = us + o; o += (size_t)2048*128;
    unsigned short* CSq_h = us + o; o += (size_t)2048*128;
    unsigned short* CSq_l = us + o; o += (size_t)2048*128;
    unsigned short* Ah    = us + o; o += (size_t)2*1024*1024;
    unsigned short* Al    = us + o; o += (size_t)2*1024*1024;
    float* Rp = (float*)(us + o);   o += (size_t)4 * 2048*512 * 2;  // 4 f32 chunks

    // barrier control block at the tail of ws (zeroed every call)
    unsigned* bars = (unsigned*)((char*)d_ws + ws_size - 256);
    hipMemsetAsync(bars, 0, 64, stream);

    mega<<<NBLK, 256, 0, stream>>>(
        x, Wk1, bk1, Wk2, bk2, Wq1, bq1, Wq2, bq2, Wv, bv, lng, lnb, Wo, bo,
        out,
        Wt_h, Wt_l, XYh, XYl, Hk_h, Hk_l, Hq_h, Hq_l, Vt_h, Vt_l,
        CSk_h, CSk_l, CSq_h, CSq_l, Ah, Al, Rp, bars);
}

// Round 8
// 286.279 us; speedup vs baseline: 2.0408x; 2.0408x over previous
//
#include <hip/hip_runtime.h>
#include <math.h>

#define L_SEQ 1024
#define M_ROWS 2048
#define PI_F 3.14159265358979323846f
#define NBLK 256

typedef short bf16x8 __attribute__((ext_vector_type(8)));
typedef float f32x4 __attribute__((ext_vector_type(4)));

__device__ __forceinline__ unsigned short bf16_rne(float x) {
    union { float f; unsigned u; } v; v.f = x;
    unsigned r = v.u + 0x7fffu + ((v.u >> 16) & 1u);
    return (unsigned short)(r >> 16);
}
__device__ __forceinline__ float bf16_tof(unsigned short h) {
    union { unsigned u; float f; } v; v.u = ((unsigned)h) << 16;
    return v.f;
}
__device__ __forceinline__ void split2(float x, unsigned short &h, unsigned short &l) {
    h = bf16_rne(x);
    l = bf16_rne(x - bf16_tof(h));
}
__device__ __forceinline__ float gelu_exact(float x) {
    return 0.5f * x * (1.0f + erff(x * 0.70710678118654752f));
}
__device__ __forceinline__ f32x4 mfma16(bf16x8 a, bf16x8 b, f32x4 c) {
    return __builtin_amdgcn_mfma_f32_16x16x32_bf16(a, b, c, 0, 0, 0);
}
__device__ __forceinline__ void gload_lds16(const unsigned short* g, unsigned short* l) {
    __builtin_amdgcn_global_load_lds(
        (const __attribute__((address_space(1))) void*)g,
        (__attribute__((address_space(3))) void*)l, 16, 0, 0);
}

// Stage one [R rows x 32 k] bf16 tile into LDS (row = 64B), pre-swizzled src.
__device__ __forceinline__ void stage_tile(
    const unsigned short* __restrict__ src, int ld, int rowBase, int k0,
    unsigned short* lds_tile, int R)
{
    const int tid = threadIdx.x;
    for (int i = 0; i < (R >> 6); ++i) {
        const int r = i * 64 + (tid >> 2);
        const int c = (tid & 3) ^ ((r >> 1) & 3);
        const unsigned short* g = src + (size_t)(rowBase + r) * ld + k0 + c * 8;
        unsigned short* l = lds_tile + i * 2048 + (tid & 192) * 8;  // wave-uniform
        gload_lds16(g, l);
    }
}

// LDS-staged split-bf16 GEMM core. 256 threads = 4 waves (2x2).
// Block tile = (MI*32) x (NI*32). A/B: [rows][k] row-major, k-contiguous.
template<int MI, int NI>
__device__ __forceinline__ void lds_gemm(
    unsigned short* lds,
    const unsigned short* Ah_, const unsigned short* Al_, int lda, int aRow,
    const unsigned short* Bh_, const unsigned short* Bl_, int ldb, int bRow,
    int k0, int nk, f32x4 (&acc)[MI][NI])
{
    constexpr int SZA = MI * 32 * 32;
    constexpr int SZB = NI * 32 * 32;
    constexpr int BUF = 2 * SZA + 2 * SZB;
    const int tid = threadIdx.x, lane = tid & 63;
    const int wm = (tid >> 7) & 1, wn = (tid >> 6) & 1;

    stage_tile(Ah_, lda, aRow, k0, lds,                 MI * 32);
    stage_tile(Al_, lda, aRow, k0, lds + SZA,           MI * 32);
    stage_tile(Bh_, ldb, bRow, k0, lds + 2 * SZA,       NI * 32);
    stage_tile(Bl_, ldb, bRow, k0, lds + 2 * SZA + SZB, NI * 32);

    for (int ks = 0; ks < nk; ++ks) {
        const int cur = (ks & 1) * BUF;
        const int nxt = ((ks & 1) ^ 1) * BUF;
        __syncthreads();
        if (ks + 1 < nk) {
            const int kk = k0 + (ks + 1) * 32;
            stage_tile(Ah_, lda, aRow, kk, lds + nxt,                 MI * 32);
            stage_tile(Al_, lda, aRow, kk, lds + nxt + SZA,           MI * 32);
            stage_tile(Bh_, ldb, bRow, kk, lds + nxt + 2 * SZA,       NI * 32);
            stage_tile(Bl_, ldb, bRow, kk, lds + nxt + 2 * SZA + SZB, NI * 32);
        }
        const int lr = lane & 15, j = lane >> 4;
        bf16x8 ah[MI], al[MI], bh[NI], bl[NI];
#pragma unroll
        for (int mi = 0; mi < MI; ++mi) {
            const int r = wm * (MI * 16) + mi * 16 + lr;
            const int off = cur + r * 32 + ((j ^ ((r >> 1) & 3)) << 3);
            ah[mi] = *(const bf16x8*)(lds + off);
            al[mi] = *(const bf16x8*)(lds + off + SZA);
        }
#pragma unroll
        for (int ni = 0; ni < NI; ++ni) {
            const int r = wn * (NI * 16) + ni * 16 + lr;
            const int off = cur + 2 * SZA + r * 32 + ((j ^ ((r >> 1) & 3)) << 3);
            bh[ni] = *(const bf16x8*)(lds + off);
            bl[ni] = *(const bf16x8*)(lds + off + SZB);
        }
#pragma unroll
        for (int mi = 0; mi < MI; ++mi)
#pragma unroll
            for (int ni = 0; ni < NI; ++ni) {
                acc[mi][ni] = mfma16(ah[mi], bh[ni], acc[mi][ni]);
                acc[mi][ni] = mfma16(ah[mi], bl[ni], acc[mi][ni]);
                acc[mi][ni] = mfma16(al[mi], bh[ni], acc[mi][ni]);
            }
    }
}

// Device-scope grid barrier, relaxed-spin version.
// Release fence (wbl2) ONCE before arrival; pollers spin on RELAXED
// coherent-point loads (no L2 invalidate per poll!); ONE acquire fence
// (buffer_inv) after the flag flips. bars zeroed by hipMemsetAsync.
__device__ __forceinline__ void grid_barrier(unsigned* bars, int id) {
    __syncthreads();
    if (threadIdx.x == 0) {
        __builtin_amdgcn_fence(__ATOMIC_RELEASE, "agent");
        unsigned old = __hip_atomic_fetch_add(&bars[id * 2], 1u,
                          __ATOMIC_RELAXED, __HIP_MEMORY_SCOPE_AGENT);
        if (old == NBLK - 1) {
            __hip_atomic_store(&bars[id * 2 + 1], 1u,
                          __ATOMIC_RELAXED, __HIP_MEMORY_SCOPE_AGENT);
        } else {
            while (!__hip_atomic_load(&bars[id * 2 + 1],
                          __ATOMIC_RELAXED, __HIP_MEMORY_SCOPE_AGENT))
                __builtin_amdgcn_s_sleep(4);
        }
        __builtin_amdgcn_fence(__ATOMIC_ACQUIRE, "agent");
    }
    __syncthreads();
}

// ---------------------------------------------------------------------------
// One persistent kernel: prep | qkv | phase | scores | av | ln | out
// ---------------------------------------------------------------------------
__global__ __launch_bounds__(256) void mega(
    const float* x,
    const float* Wk1, const float* bk1, const float* Wk2, const float* bk2,
    const float* Wq1, const float* bq1, const float* Wq2, const float* bq2,
    const float* Wv,  const float* bv,
    const float* lng, const float* lnb,
    const float* Wo,  const float* bo,
    float* out,
    unsigned short* Wt_h, unsigned short* Wt_l,
    unsigned short* XYh,  unsigned short* XYl,   // X (phase B) then Y (phase F+)
    unsigned short* Hk_h, unsigned short* Hk_l,
    unsigned short* Hq_h, unsigned short* Hq_l,
    unsigned short* Vt_h, unsigned short* Vt_l,
    unsigned short* CSk_h, unsigned short* CSk_l,
    unsigned short* CSq_h, unsigned short* CSq_l,
    unsigned short* Ah, unsigned short* Al,
    float* Rp,
    unsigned* bars)
{
    __shared__ __align__(16) unsigned short lds[32768];   // 64KB, reused per phase
    const int bid = blockIdx.x;
    const int tid = threadIdx.x;
    const int lane = tid & 63, wid = tid >> 6;

    // ---------------- Phase A: prep (W transpose+split, X split) ------------
    for (int u = bid; u < 272; u += NBLK) {
        const int kT = u & 7, ty = u >> 3;
        const float* src; int srcN, dstRowBase, nBase;
        if (ty < 8)       { src = Wk1; srcN = 512; dstRowBase = 0;    nBase = ty * 64; }
        else if (ty < 16) { src = Wq1; srcN = 512; dstRowBase = 512;  nBase = (ty-8)*64; }
        else if (ty < 24) { src = Wv;  srcN = 512; dstRowBase = 1024; nBase = (ty-16)*64; }
        else if (ty < 32) { src = Wo;  srcN = 512; dstRowBase = 1536; nBase = (ty-24)*64; }
        else if (ty == 32){ src = Wk2; srcN = 64;  dstRowBase = 2048; nBase = 0; }
        else              { src = Wq2; srcN = 64;  dstRowBase = 2112; nBase = 0; }
        float* T = (float*)lds;   // [64][65]
        const int k0 = kT * 64;
        {
            const int r = tid >> 2, c0 = (tid & 3) * 16;
#pragma unroll
            for (int i = 0; i < 4; ++i) {
                float4 v = *reinterpret_cast<const float4*>(
                    src + (size_t)(k0 + r) * srcN + nBase + c0 + i*4);
                T[r*65 + c0+i*4+0] = v.x; T[r*65 + c0+i*4+1] = v.y;
                T[r*65 + c0+i*4+2] = v.z; T[r*65 + c0+i*4+3] = v.w;
            }
        }
        __syncthreads();
        {
            const int n = tid >> 2, kk0 = (tid & 3) * 16;
            const size_t base = (size_t)(dstRowBase + nBase + n) * 512 + k0 + kk0;
#pragma unroll
            for (int i = 0; i < 16; ++i) {
                unsigned short h, l;
                split2(T[(kk0 + i)*65 + n], h, l);
                Wt_h[base + i] = h; Wt_l[base + i] = l;
            }
        }
        __syncthreads();
    }
    {   // X split: 262144 float4 over 256 blocks
#pragma unroll
        for (int ii = 0; ii < 4; ++ii) {
            const size_t i = (size_t)bid * 1024 + ii * 256 + tid;
            float4 v = reinterpret_cast<const float4*>(x)[i];
            unsigned short h0,h1,h2,h3,l0,l1,l2,l3;
            split2(v.x,h0,l0); split2(v.y,h1,l1); split2(v.z,h2,l2); split2(v.w,h3,l3);
            unsigned long long hp = (unsigned long long)h0 | ((unsigned long long)h1<<16)
                                  | ((unsigned long long)h2<<32) | ((unsigned long long)h3<<48);
            unsigned long long lp = (unsigned long long)l0 | ((unsigned long long)l1<<16)
                                  | ((unsigned long long)l2<<32) | ((unsigned long long)l3<<48);
            reinterpret_cast<unsigned long long*>(XYh)[i] = hp;
            reinterpret_cast<unsigned long long*>(XYl)[i] = lp;
        }
    }
    grid_barrier(bars, 0);

    // ---------------- Phase B: fused QKV (192 tiles of 128x128) -------------
    if (bid < 192) {
        const int nT = bid % 12, mT = bid / 12;
        const int mBase = mT * 128, nBase = nT * 128;
        const int wm = (tid >> 7) & 1, wn = (tid >> 6) & 1;
        f32x4 acc[4][4];
#pragma unroll
        for (int i = 0; i < 4; ++i)
#pragma unroll
            for (int jj = 0; jj < 4; ++jj) acc[i][jj] = (f32x4){0.f,0.f,0.f,0.f};
        lds_gemm<4,4>(lds, XYh, XYl, 512, mBase, Wt_h, Wt_l, 512, nBase, 0, 16, acc);
        const int seg = nBase >> 9;
        const float* bias = (seg == 0) ? bk1 : (seg == 1) ? bq1 : bv;
#pragma unroll
        for (int mi = 0; mi < 4; ++mi)
#pragma unroll
        for (int ni = 0; ni < 4; ++ni)
#pragma unroll
        for (int r = 0; r < 4; ++r) {
            const int row = mBase + wm*64 + mi*16 + (lane>>4)*4 + r;
            const int col = nBase + wn*64 + ni*16 + (lane&15);
            const int nW = col & 511;
            float v = acc[mi][ni][r] + bias[nW];
            if (seg < 2) v = gelu_exact(v);
            unsigned short h, l;
            split2(v, h, l);
            if (seg == 0)      { Hk_h[(size_t)row*512 + nW] = h; Hk_l[(size_t)row*512 + nW] = l; }
            else if (seg == 1) { Hq_h[(size_t)row*512 + nW] = h; Hq_l[(size_t)row*512 + nW] = l; }
            else {
                const size_t o = (size_t)((row >> 10)*512 + nW) * 1024 + (row & 1023);
                Vt_h[o] = h; Vt_l[o] = l;
            }
        }
    }
    grid_barrier(bars, 1);

    // ---------------- Phase C: phase heads (64 tiles of 64x64) --------------
    if (bid < 64) {
        const int enc = bid & 1, mT = bid >> 1;
        const unsigned short* Ah_ = enc ? Hq_h : Hk_h;
        const unsigned short* Al_ = enc ? Hq_l : Hk_l;
        const float* b2 = enc ? bq2 : bk2;
        unsigned short* Ch = enc ? CSq_h : CSk_h;
        unsigned short* Cl = enc ? CSq_l : CSk_l;
        const int wm = (tid >> 7) & 1, wn = (tid >> 6) & 1;
        f32x4 acc[2][2];
#pragma unroll
        for (int i = 0; i < 2; ++i)
#pragma unroll
            for (int jj = 0; jj < 2; ++jj) acc[i][jj] = (f32x4){0.f,0.f,0.f,0.f};
        lds_gemm<2,2>(lds, Ah_, Al_, 512, mT*64, Wt_h, Wt_l, 512, 2048 + enc*64, 0, 16, acc);
#pragma unroll
        for (int mi = 0; mi < 2; ++mi)
#pragma unroll
        for (int ni = 0; ni < 2; ++ni)
#pragma unroll
        for (int r = 0; r < 4; ++r) {
            const int row = mT*64 + wm*32 + mi*16 + (lane>>4)*4 + r;
            const int j = wn*32 + ni*16 + (lane&15);
            float p = acc[mi][ni][r] + b2[j];
            p = tanhf(p) * PI_F;
            float s, c;
            sincosf(p, &s, &c);
            unsigned short h, l;
            split2(c, h, l);
            Ch[(size_t)row*128 + j] = h; Cl[(size_t)row*128 + j] = l;
            split2(s, h, l);
            Ch[(size_t)row*128 + 64 + j] = h; Cl[(size_t)row*128 + 64 + j] = l;
        }
    }
    grid_barrier(bars, 2);

    // ---------------- Phase D: scores (lower-tri 128x128 tiles) -------------
    if (bid < 128) {
        const int sT = bid & 7, tT = (bid >> 3) & 7, b = bid >> 6;
        if (sT <= tT) {
            const int wm = (tid >> 7) & 1, wn = (tid >> 6) & 1;
            f32x4 acc[4][4];
#pragma unroll
            for (int i = 0; i < 4; ++i)
#pragma unroll
                for (int jj = 0; jj < 4; ++jj) acc[i][jj] = (f32x4){0.f,0.f,0.f,0.f};
            lds_gemm<4,4>(lds, CSq_h, CSq_l, 128, b*1024 + tT*128,
                          CSk_h, CSk_l, 128, b*1024 + sT*128, 0, 4, acc);
#pragma unroll
            for (int mi = 0; mi < 4; ++mi)
#pragma unroll
            for (int ni = 0; ni < 4; ++ni)
#pragma unroll
            for (int r = 0; r < 4; ++r) {
                const int t = tT*128 + wm*64 + mi*16 + (lane>>4)*4 + r;
                const int s = sT*128 + wn*64 + ni*16 + (lane&15);
                float v = (s <= t) ? acc[mi][ni][r] : 0.f;
                unsigned short h, l;
                split2(v, h, l);
                const size_t o = ((size_t)b*1024 + t) * 1024 + s;
                Ah[o] = h; Al[o] = l;
            }
        }
    }
    grid_barrier(bars, 3);

    // ---------------- Phase E: causal AV (s-chunked partials) ---------------
    {
        const int dT = bid & 3, tT = (bid >> 2) & 7, b = (bid >> 5) & 1, c = bid >> 6;
        if (c <= (tT >> 1)) {
            const int wm = (tid >> 7) & 1, wn = (tid >> 6) & 1;
            const int kLen = min(256, tT*128 + 128 - c*256);
            const int nk = kLen >> 5;
            f32x4 acc[4][4];
#pragma unroll
            for (int i = 0; i < 4; ++i)
#pragma unroll
                for (int jj = 0; jj < 4; ++jj) acc[i][jj] = (f32x4){0.f,0.f,0.f,0.f};
            lds_gemm<4,4>(lds, Ah, Al, 1024, b*1024 + tT*128,
                          Vt_h, Vt_l, 1024, b*512 + dT*128, c*256, nk, acc);
            float* Rb = Rp + (size_t)c * (M_ROWS * 512);
#pragma unroll
            for (int mi = 0; mi < 4; ++mi)
#pragma unroll
            for (int ni = 0; ni < 4; ++ni)
#pragma unroll
            for (int r = 0; r < 4; ++r) {
                const int row = b*1024 + tT*128 + wm*64 + mi*16 + (lane>>4)*4 + r;
                const int d = dT*128 + wn*64 + ni*16 + (lane&15);
                Rb[(size_t)row*512 + d] = acc[mi][ni][r];
            }
        }
    }
    grid_barrier(bars, 4);

    // ---------------- Phase F: LayerNorm -> Y (bf16 split, into XY*) --------
    {
        float* fbuf = (float*)lds;
        for (int i = 0; i < 8; ++i) {
            const int row = bid * 8 + i;
            const int t = row & (L_SEQ - 1);
            const int nc = (t >> 8) + 1;
            const float scale = rsqrtf((float)(t + 1) * 64.0f);
            float v0 = 0.f, v1 = 0.f;
            for (int c = 0; c < nc; ++c) {
                const float* Rr = Rp + (size_t)c * (M_ROWS * 512) + (size_t)row * 512;
                v0 += Rr[tid];
                v1 += Rr[256 + tid];
            }
            v0 *= scale; v1 *= scale;
            float s = v0 + v1, q = v0*v0 + v1*v1;
#pragma unroll
            for (int off = 32; off >= 1; off >>= 1) {
                s += __shfl_down(s, off);
                q += __shfl_down(q, off);
            }
            if (lane == 0) { fbuf[wid] = s; fbuf[4 + wid] = q; }
            __syncthreads();
            const float S = fbuf[0] + fbuf[1] + fbuf[2] + fbuf[3];
            const float Q = fbuf[4] + fbuf[5] + fbuf[6] + fbuf[7];
            const float mu  = S * (1.f / 512.f);
            const float var = Q * (1.f / 512.f) - mu * mu;
            const float rr = rsqrtf(var + 1e-5f);
            const float y0 = (v0 - mu) * rr * lng[tid]       + lnb[tid];
            const float y1 = (v1 - mu) * rr * lng[256 + tid] + lnb[256 + tid];
            unsigned short h, l;
            split2(y0, h, l);
            XYh[(size_t)row*512 + tid] = h;       XYl[(size_t)row*512 + tid] = l;
            split2(y1, h, l);
            XYh[(size_t)row*512 + 256 + tid] = h; XYl[(size_t)row*512 + 256 + tid] = l;
            __syncthreads();
        }
    }
    grid_barrier(bars, 5);

    // ---------------- Phase G: out = x + Y @ Wo + bo (256 tiles 64x64) ------
    {
        const int nT = bid & 7, mT = bid >> 3;
        const int wm = (tid >> 7) & 1, wn = (tid >> 6) & 1;
        f32x4 acc[2][2];
#pragma unroll
        for (int i = 0; i < 2; ++i)
#pragma unroll
            for (int jj = 0; jj < 2; ++jj) acc[i][jj] = (f32x4){0.f,0.f,0.f,0.f};
        lds_gemm<2,2>(lds, XYh, XYl, 512, mT*64, Wt_h, Wt_l, 512, 1536 + nT*64, 0, 16, acc);
#pragma unroll
        for (int mi = 0; mi < 2; ++mi)
#pragma unroll
        for (int ni = 0; ni < 2; ++ni)
#pragma unroll
        for (int r = 0; r < 4; ++r) {
            const int row = mT*64 + wm*32 + mi*16 + (lane>>4)*4 + r;
            const int col = nT*64 + wn*32 + ni*16 + (lane&15);
            out[(size_t)row*512 + col] =
                acc[mi][ni][r] + bo[col] + x[(size_t)row*512 + col];
        }
    }
}

// ---------------------------------------------------------------------------
extern "C" void kernel_launch(void* const* d_in, const int* in_sizes, int n_in,
                              void* d_out, int out_size, void* d_ws, size_t ws_size,
                              hipStream_t stream)
{
    const float* x   = (const float*)d_in[0];
    const float* Wk1 = (const float*)d_in[1];
    const float* bk1 = (const float*)d_in[2];
    const float* Wk2 = (const float*)d_in[3];
    const float* bk2 = (const float*)d_in[4];
    const float* Wq1 = (const float*)d_in[5];
    const float* bq1 = (const float*)d_in[6];
    const float* Wq2 = (const float*)d_in[7];
    const float* bq2 = (const float*)d_in[8];
    const float* Wv  = (const float*)d_in[9];
    const float* bv  = (const float*)d_in[10];
    const float* lng = (const float*)d_in[11];
    const float* lnb = (const float*)d_in[12];
    const float* Wo  = (const float*)d_in[13];
    const float* bo  = (const float*)d_in[14];
    float* out = (float*)d_out;

    unsigned short* us = (unsigned short*)d_ws;
    size_t o = 0;
    unsigned short* Wt_h  = us + o; o += (size_t)2176*512;
    unsigned short* Wt_l  = us + o; o += (size_t)2176*512;
    unsigned short* XYh   = us + o; o += (size_t)2048*512;
    unsigned short* XYl   = us + o; o += (size_t)2048*512;
    unsigned short* Hk_h  = us + o; o += (size_t)2048*512;
    unsigned short* Hk_l  = us + o; o += (size_t)2048*512;
    unsigned short* Hq_h  = us + o; o += (size_t)2048*512;
    unsigned short* Hq_l  = us + o; o += (size_t)2048*512;
    unsigned short* Vt_h  = us + o; o += (size_t)2*512*1024;
    unsigned short* Vt_l  = us + o; o += (size_t)2*512*1024;
    unsigned short* CSk_h = us + o; o += (size_t)2048*128;
    unsigned short* CSk_l = us + o; o += (size_t)2048*128;
    unsigned short* CSq_h = us + o; o += (size_t)2048*128;
    unsigned short* CSq_l = us + o; o += (size_t)2048*128;
    unsigned short* Ah    = us + o; o += (size_t)2*1024*1024;
    unsigned short* Al    = us + o; o += (size_t)2*1024*1024;
    float* Rp = (float*)(us + o);   o += (size_t)4 * 2048*512 * 2;  // 4 f32 chunks

    // barrier control block at the tail of ws (zeroed every call)
    unsigned* bars = (unsigned*)((char*)d_ws + ws_size - 256);
    (void)hipMemsetAsync(bars, 0, 64, stream);

    mega<<<NBLK, 256, 0, stream>>>(
        x, Wk1, bk1, Wk2, bk2, Wq1, bq1, Wq2, bq2, Wv, bv, lng, lnb, Wo, bo,
        out,
        Wt_h, Wt_l, XYh, XYl, Hk_h, Hk_l, Hq_h, Hq_l, Vt_h, Vt_l,
        CSk_h, CSk_l, CSq_h, CSq_l, Ah, Al, Rp, bars);
}

// Round 9
// 277.998 us; speedup vs baseline: 2.1016x; 1.0298x over previous
//
#include <hip/hip_runtime.h>
#include <math.h>

#define L_SEQ 1024
#define M_ROWS 2048
#define PI_F 3.14159265358979323846f
#define NBLK 256
#define NTHR 512

typedef short bf16x8 __attribute__((ext_vector_type(8)));
typedef float f32x4 __attribute__((ext_vector_type(4)));

__device__ __forceinline__ unsigned short bf16_rne(float x) {
    union { float f; unsigned u; } v; v.f = x;
    unsigned r = v.u + 0x7fffu + ((v.u >> 16) & 1u);
    return (unsigned short)(r >> 16);
}
__device__ __forceinline__ float bf16_tof(unsigned short h) {
    union { unsigned u; float f; } v; v.u = ((unsigned)h) << 16;
    return v.f;
}
__device__ __forceinline__ void split2(float x, unsigned short &h, unsigned short &l) {
    h = bf16_rne(x);
    l = bf16_rne(x - bf16_tof(h));
}
__device__ __forceinline__ float gelu_exact(float x) {
    return 0.5f * x * (1.0f + erff(x * 0.70710678118654752f));
}
__device__ __forceinline__ f32x4 mfma16(bf16x8 a, bf16x8 b, f32x4 c) {
    return __builtin_amdgcn_mfma_f32_16x16x32_bf16(a, b, c, 0, 0, 0);
}
__device__ __forceinline__ void gload_lds16(const unsigned short* g, unsigned short* l) {
    __builtin_amdgcn_global_load_lds(
        (const __attribute__((address_space(1))) void*)g,
        (__attribute__((address_space(3))) void*)l, 16, 0, 0);
}

// Stage R x 32 bf16 tile into LDS (row = 64B), pre-swizzled source.
// 512 threads: R=128 uses all 8 waves; R=64 uses waves 0-3.
__device__ __forceinline__ void stage_tile(
    const unsigned short* __restrict__ src, int ld, int rowBase, int k0,
    unsigned short* lds_tile, int R)
{
    const int tid = threadIdx.x;
    if (R == 128 || tid < 256) {
        const int r = tid >> 2;                      // tile row
        const int c = (tid & 3) ^ ((r >> 1) & 3);    // swizzled src k-slot
        const unsigned short* g = src + (size_t)(rowBase + r) * ld + k0 + c * 8;
        unsigned short* l = lds_tile + (tid >> 6) * 512;   // wave-uniform base
        gload_lds16(g, l);
    }
}

// LDS-staged split-bf16 GEMM core. 512 threads = 8 waves (2m x 4n).
// Block tile = (32*MI) x (64*NI). A rows = 32*MI, B rows = 64*NI, K-step 32.
template<int MI, int NI>
__device__ __forceinline__ void lds_gemm(
    unsigned short* lds,
    const unsigned short* Ah_, const unsigned short* Al_, int lda, int aRow,
    const unsigned short* Bh_, const unsigned short* Bl_, int ldb, int bRow,
    int k0, int nk, f32x4 (&acc)[MI][NI])
{
    constexpr int RA = MI * 32, RB = NI * 64;
    constexpr int SZA = RA * 32;
    constexpr int SZB = RB * 32;
    constexpr int BUF = 2 * SZA + 2 * SZB;
    const int tid = threadIdx.x, lane = tid & 63;
    const int wm = (tid >> 8) & 1;       // wave row (0..1)
    const int wn = (tid >> 6) & 3;       // wave col (0..3)

    stage_tile(Ah_, lda, aRow, k0, lds,                 RA);
    stage_tile(Al_, lda, aRow, k0, lds + SZA,           RA);
    stage_tile(Bh_, ldb, bRow, k0, lds + 2 * SZA,       RB);
    stage_tile(Bl_, ldb, bRow, k0, lds + 2 * SZA + SZB, RB);

    for (int ks = 0; ks < nk; ++ks) {
        const int cur = (ks & 1) * BUF;
        const int nxt = ((ks & 1) ^ 1) * BUF;
        __syncthreads();
        if (ks + 1 < nk) {
            const int kk = k0 + (ks + 1) * 32;
            stage_tile(Ah_, lda, aRow, kk, lds + nxt,                 RA);
            stage_tile(Al_, lda, aRow, kk, lds + nxt + SZA,           RA);
            stage_tile(Bh_, ldb, bRow, kk, lds + nxt + 2 * SZA,       RB);
            stage_tile(Bl_, ldb, bRow, kk, lds + nxt + 2 * SZA + SZB, RB);
        }
        const int lr = lane & 15, j = lane >> 4;
        bf16x8 ah[MI], al[MI], bh[NI], bl[NI];
#pragma unroll
        for (int mi = 0; mi < MI; ++mi) {
            const int r = wm * (MI * 16) + mi * 16 + lr;
            const int off = cur + r * 32 + ((j ^ ((r >> 1) & 3)) << 3);
            ah[mi] = *(const bf16x8*)(lds + off);
            al[mi] = *(const bf16x8*)(lds + off + SZA);
        }
#pragma unroll
        for (int ni = 0; ni < NI; ++ni) {
            const int r = wn * (NI * 16) + ni * 16 + lr;
            const int off = cur + 2 * SZA + r * 32 + ((j ^ ((r >> 1) & 3)) << 3);
            bh[ni] = *(const bf16x8*)(lds + off);
            bl[ni] = *(const bf16x8*)(lds + off + SZB);
        }
#pragma unroll
        for (int mi = 0; mi < MI; ++mi)
#pragma unroll
            for (int ni = 0; ni < NI; ++ni) {
                acc[mi][ni] = mfma16(ah[mi], bh[ni], acc[mi][ni]);
                acc[mi][ni] = mfma16(ah[mi], bl[ni], acc[mi][ni]);
                acc[mi][ni] = mfma16(al[mi], bh[ni], acc[mi][ni]);
            }
    }
}

// Device-scope grid barrier, relaxed-spin. One release fence before arrival,
// relaxed polls, one acquire fence after flag.
__device__ __forceinline__ void grid_barrier(unsigned* bars, int id) {
    __syncthreads();
    if (threadIdx.x == 0) {
        __builtin_amdgcn_fence(__ATOMIC_RELEASE, "agent");
        unsigned old = __hip_atomic_fetch_add(&bars[id * 2], 1u,
                          __ATOMIC_RELAXED, __HIP_MEMORY_SCOPE_AGENT);
        if (old == NBLK - 1) {
            __hip_atomic_store(&bars[id * 2 + 1], 1u,
                          __ATOMIC_RELAXED, __HIP_MEMORY_SCOPE_AGENT);
        } else {
            while (!__hip_atomic_load(&bars[id * 2 + 1],
                          __ATOMIC_RELAXED, __HIP_MEMORY_SCOPE_AGENT))
                __builtin_amdgcn_s_sleep(4);
        }
        __builtin_amdgcn_fence(__ATOMIC_ACQUIRE, "agent");
    }
    __syncthreads();
}

// ---------------------------------------------------------------------------
// One persistent kernel, 256 blocks x 512 threads (8 waves/CU).
// ---------------------------------------------------------------------------
__global__ __launch_bounds__(512) void mega(
    const float* x,
    const float* Wk1, const float* bk1, const float* Wk2, const float* bk2,
    const float* Wq1, const float* bq1, const float* Wq2, const float* bq2,
    const float* Wv,  const float* bv,
    const float* lng, const float* lnb,
    const float* Wo,  const float* bo,
    float* out,
    unsigned short* Wt_h, unsigned short* Wt_l,
    unsigned short* XYh,  unsigned short* XYl,
    unsigned short* Hk_h, unsigned short* Hk_l,
    unsigned short* Hq_h, unsigned short* Hq_l,
    unsigned short* Vt_h, unsigned short* Vt_l,
    unsigned short* CSk_h, unsigned short* CSk_l,
    unsigned short* CSq_h, unsigned short* CSq_l,
    unsigned short* Ah, unsigned short* Al,
    float* Rp,
    unsigned* bars)
{
    __shared__ __align__(16) unsigned short lds[32768];   // 64KB
    const int bid = blockIdx.x;
    const int tid = threadIdx.x;
    const int lane = tid & 63, wid = tid >> 6;

    // ---------------- Phase A: prep (W transpose+split, X split) ------------
    for (int u = bid; u < 272; u += NBLK) {
        const int kT = u & 7, ty = u >> 3;
        const float* src; int srcN, dstRowBase, nBase;
        if (ty < 8)       { src = Wk1; srcN = 512; dstRowBase = 0;    nBase = ty * 64; }
        else if (ty < 16) { src = Wq1; srcN = 512; dstRowBase = 512;  nBase = (ty-8)*64; }
        else if (ty < 24) { src = Wv;  srcN = 512; dstRowBase = 1024; nBase = (ty-16)*64; }
        else if (ty < 32) { src = Wo;  srcN = 512; dstRowBase = 1536; nBase = (ty-24)*64; }
        else if (ty == 32){ src = Wk2; srcN = 64;  dstRowBase = 2048; nBase = 0; }
        else              { src = Wq2; srcN = 64;  dstRowBase = 2112; nBase = 0; }
        float* T = (float*)lds;   // [64][65]
        const int k0 = kT * 64;
        {
            const int r = tid >> 3, c0 = (tid & 7) * 8;   // 64 rows x 8 cols each
#pragma unroll
            for (int i = 0; i < 2; ++i) {
                float4 v = *reinterpret_cast<const float4*>(
                    src + (size_t)(k0 + r) * srcN + nBase + c0 + i*4);
                T[r*65 + c0+i*4+0] = v.x; T[r*65 + c0+i*4+1] = v.y;
                T[r*65 + c0+i*4+2] = v.z; T[r*65 + c0+i*4+3] = v.w;
            }
        }
        __syncthreads();
        {
            const int n = tid >> 3, kk0 = (tid & 7) * 8;
            const size_t base = (size_t)(dstRowBase + nBase + n) * 512 + k0 + kk0;
#pragma unroll
            for (int i = 0; i < 8; ++i) {
                unsigned short h, l;
                split2(T[(kk0 + i)*65 + n], h, l);
                Wt_h[base + i] = h; Wt_l[base + i] = l;
            }
        }
        __syncthreads();
    }
    {   // X split: 262144 float4 over 256 blocks x 512 threads
#pragma unroll
        for (int ii = 0; ii < 2; ++ii) {
            const size_t i = (size_t)bid * 1024 + ii * 512 + tid;
            float4 v = reinterpret_cast<const float4*>(x)[i];
            unsigned short h0,h1,h2,h3,l0,l1,l2,l3;
            split2(v.x,h0,l0); split2(v.y,h1,l1); split2(v.z,h2,l2); split2(v.w,h3,l3);
            unsigned long long hp = (unsigned long long)h0 | ((unsigned long long)h1<<16)
                                  | ((unsigned long long)h2<<32) | ((unsigned long long)h3<<48);
            unsigned long long lp = (unsigned long long)l0 | ((unsigned long long)l1<<16)
                                  | ((unsigned long long)l2<<32) | ((unsigned long long)l3<<48);
            reinterpret_cast<unsigned long long*>(XYh)[i] = hp;
            reinterpret_cast<unsigned long long*>(XYl)[i] = lp;
        }
    }
    grid_barrier(bars, 0);

    // ---------------- Phase B: fused QKV (192 units of 128x128) -------------
    if (bid < 192) {
        const int nT = bid % 12, mT = bid / 12;
        const int mBase = mT * 128, nBase = nT * 128;
        const int wm = (tid >> 8) & 1, wn = (tid >> 6) & 3;
        f32x4 acc[4][2];
#pragma unroll
        for (int i = 0; i < 4; ++i)
#pragma unroll
            for (int jj = 0; jj < 2; ++jj) acc[i][jj] = (f32x4){0.f,0.f,0.f,0.f};
        lds_gemm<4,2>(lds, XYh, XYl, 512, mBase, Wt_h, Wt_l, 512, nBase, 0, 16, acc);
        const int seg = nBase >> 9;
        const float* bias = (seg == 0) ? bk1 : (seg == 1) ? bq1 : bv;
#pragma unroll
        for (int mi = 0; mi < 4; ++mi)
#pragma unroll
        for (int ni = 0; ni < 2; ++ni)
#pragma unroll
        for (int r = 0; r < 4; ++r) {
            const int row = mBase + wm*64 + mi*16 + (lane>>4)*4 + r;
            const int col = nBase + wn*32 + ni*16 + (lane&15);
            const int nW = col & 511;
            float v = acc[mi][ni][r] + bias[nW];
            if (seg < 2) v = gelu_exact(v);
            unsigned short h, l;
            split2(v, h, l);
            if (seg == 0)      { Hk_h[(size_t)row*512 + nW] = h; Hk_l[(size_t)row*512 + nW] = l; }
            else if (seg == 1) { Hq_h[(size_t)row*512 + nW] = h; Hq_l[(size_t)row*512 + nW] = l; }
            else {
                const size_t o = (size_t)((row >> 10)*512 + nW) * 1024 + (row & 1023);
                Vt_h[o] = h; Vt_l[o] = l;
            }
        }
    }
    grid_barrier(bars, 1);

    // ---------------- Phase C: phase heads (64 units of 64x64) --------------
    if (bid < 64) {
        const int enc = bid & 1, mT = bid >> 1;
        const unsigned short* Ah_ = enc ? Hq_h : Hk_h;
        const unsigned short* Al_ = enc ? Hq_l : Hk_l;
        const float* b2 = enc ? bq2 : bk2;
        unsigned short* Ch = enc ? CSq_h : CSk_h;
        unsigned short* Cl = enc ? CSq_l : CSk_l;
        const int wm = (tid >> 8) & 1, wn = (tid >> 6) & 3;
        f32x4 acc[2][1];
#pragma unroll
        for (int i = 0; i < 2; ++i) acc[i][0] = (f32x4){0.f,0.f,0.f,0.f};
        lds_gemm<2,1>(lds, Ah_, Al_, 512, mT*64, Wt_h, Wt_l, 512, 2048 + enc*64, 0, 16, acc);
#pragma unroll
        for (int mi = 0; mi < 2; ++mi)
#pragma unroll
        for (int r = 0; r < 4; ++r) {
            const int row = mT*64 + wm*32 + mi*16 + (lane>>4)*4 + r;
            const int j = wn*16 + (lane&15);
            float p = acc[mi][0][r] + b2[j];
            p = tanhf(p) * PI_F;
            float s, c;
            sincosf(p, &s, &c);
            unsigned short h, l;
            split2(c, h, l);
            Ch[(size_t)row*128 + j] = h; Cl[(size_t)row*128 + j] = l;
            split2(s, h, l);
            Ch[(size_t)row*128 + 64 + j] = h; Cl[(size_t)row*128 + 64 + j] = l;
        }
    }
    grid_barrier(bars, 2);

    // ---------------- Phase D: scores (64x128 tiles, lower-tri) -------------
    for (int u = bid; u < 256; u += NBLK) {
        const int b = u >> 7, tT = (u >> 3) & 15, sT = u & 7;
        if (sT * 128 > tT * 64 + 63) continue;
        const int wm = (tid >> 8) & 1, wn = (tid >> 6) & 3;
        f32x4 acc[2][2];
#pragma unroll
        for (int i = 0; i < 2; ++i)
#pragma unroll
            for (int jj = 0; jj < 2; ++jj) acc[i][jj] = (f32x4){0.f,0.f,0.f,0.f};
        lds_gemm<2,2>(lds, CSq_h, CSq_l, 128, b*1024 + tT*64,
                      CSk_h, CSk_l, 128, b*1024 + sT*128, 0, 4, acc);
#pragma unroll
        for (int mi = 0; mi < 2; ++mi)
#pragma unroll
        for (int ni = 0; ni < 2; ++ni)
#pragma unroll
        for (int r = 0; r < 4; ++r) {
            const int t = tT*64 + wm*32 + mi*16 + (lane>>4)*4 + r;
            const int s = sT*128 + wn*32 + ni*16 + (lane&15);
            float v = (s <= t) ? acc[mi][ni][r] : 0.f;
            unsigned short h, l;
            split2(v, h, l);
            const size_t o = ((size_t)b*1024 + t) * 1024 + s;
            Ah[o] = h; Al[o] = l;
        }
    }
    grid_barrier(bars, 3);

    // ---------------- Phase E: causal AV (s-chunks of 256, partials) --------
    for (int u = bid; u < 512; u += NBLK) {
        const int c = u >> 7, b = (u >> 6) & 1, dT = (u >> 4) & 3, tT = u & 15;
        if (c * 256 > tT * 64 + 63) continue;
        const int wm = (tid >> 8) & 1, wn = (tid >> 6) & 3;
        const int kLen = min(256, tT*64 + 64 - c*256);
        const int nk = kLen >> 5;
        f32x4 acc[2][2];
#pragma unroll
        for (int i = 0; i < 2; ++i)
#pragma unroll
            for (int jj = 0; jj < 2; ++jj) acc[i][jj] = (f32x4){0.f,0.f,0.f,0.f};
        lds_gemm<2,2>(lds, Ah, Al, 1024, b*1024 + tT*64,
                      Vt_h, Vt_l, 1024, b*512 + dT*128, c*256, nk, acc);
        float* Rb = Rp + (size_t)c * (M_ROWS * 512);
#pragma unroll
        for (int mi = 0; mi < 2; ++mi)
#pragma unroll
        for (int ni = 0; ni < 2; ++ni)
#pragma unroll
        for (int r = 0; r < 4; ++r) {
            const int row = b*1024 + tT*64 + wm*32 + mi*16 + (lane>>4)*4 + r;
            const int d = dT*128 + wn*32 + ni*16 + (lane&15);
            Rb[(size_t)row*512 + d] = acc[mi][ni][r];
        }
    }
    grid_barrier(bars, 4);

    // ---------------- Phase F: LayerNorm -> Y (bf16 split, into XY*) --------
    {
        float* fbuf = (float*)lds;
        for (int i = 0; i < 8; ++i) {
            const int row = bid * 8 + i;
            const int t = row & (L_SEQ - 1);
            const int nc = (t >> 8) + 1;
            const float scale = rsqrtf((float)(t + 1) * 64.0f);
            float v = 0.f;
            for (int c = 0; c < nc; ++c)
                v += Rp[(size_t)c * (M_ROWS * 512) + (size_t)row * 512 + tid];
            v *= scale;
            float s = v, q = v * v;
#pragma unroll
            for (int off = 32; off >= 1; off >>= 1) {
                s += __shfl_down(s, off);
                q += __shfl_down(q, off);
            }
            if (lane == 0) { fbuf[wid] = s; fbuf[8 + wid] = q; }
            __syncthreads();
            float S = 0.f, Q = 0.f;
#pragma unroll
            for (int w = 0; w < 8; ++w) { S += fbuf[w]; Q += fbuf[8 + w]; }
            const float mu  = S * (1.f / 512.f);
            const float var = Q * (1.f / 512.f) - mu * mu;
            const float rr = rsqrtf(var + 1e-5f);
            const float y = (v - mu) * rr * lng[tid] + lnb[tid];
            unsigned short h, l;
            split2(y, h, l);
            XYh[(size_t)row*512 + tid] = h;
            XYl[(size_t)row*512 + tid] = l;
            __syncthreads();
        }
    }
    grid_barrier(bars, 5);

    // ---------------- Phase G: out = x + Y @ Wo + bo (128 units 128x64) -----
    if (bid < 128) {
        const int mT = bid >> 3, nT = bid & 7;
        const int mBase = mT * 128;
        const int wm = (tid >> 8) & 1, wn = (tid >> 6) & 3;
        f32x4 acc[4][1];
#pragma unroll
        for (int i = 0; i < 4; ++i) acc[i][0] = (f32x4){0.f,0.f,0.f,0.f};
        lds_gemm<4,1>(lds, XYh, XYl, 512, mBase, Wt_h, Wt_l, 512, 1536 + nT*64, 0, 16, acc);
#pragma unroll
        for (int mi = 0; mi < 4; ++mi)
#pragma unroll
        for (int r = 0; r < 4; ++r) {
            const int row = mBase + wm*64 + mi*16 + (lane>>4)*4 + r;
            const int col = nT*64 + wn*16 + (lane&15);
            out[(size_t)row*512 + col] =
                acc[mi][0][r] + bo[col] + x[(size_t)row*512 + col];
        }
    }
}

// ---------------------------------------------------------------------------
extern "C" void kernel_launch(void* const* d_in, const int* in_sizes, int n_in,
                              void* d_out, int out_size, void* d_ws, size_t ws_size,
                              hipStream_t stream)
{
    const float* x   = (const float*)d_in[0];
    const float* Wk1 = (const float*)d_in[1];
    const float* bk1 = (const float*)d_in[2];
    const float* Wk2 = (const float*)d_in[3];
    const float* bk2 = (const float*)d_in[4];
    const float* Wq1 = (const float*)d_in[5];
    const float* bq1 = (const float*)d_in[6];
    const float* Wq2 = (const float*)d_in[7];
    const float* bq2 = (const float*)d_in[8];
    const float* Wv  = (const float*)d_in[9];
    const float* bv  = (const float*)d_in[10];
    const float* lng = (const float*)d_in[11];
    const float* lnb = (const float*)d_in[12];
    const float* Wo  = (const float*)d_in[13];
    const float* bo  = (const float*)d_in[14];
    float* out = (float*)d_out;

    unsigned short* us = (unsigned short*)d_ws;
    size_t o = 0;
    unsigned short* Wt_h  = us + o; o += (size_t)2176*512;
    unsigned short* Wt_l  = us + o; o += (size_t)2176*512;
    unsigned short* XYh   = us + o; o += (size_t)2048*512;
    unsigned short* XYl   = us + o; o += (size_t)2048*512;
    unsigned short* Hk_h  = us + o; o += (size_t)2048*512;
    unsigned short* Hk_l  = us + o; o += (size_t)2048*512;
    unsigned short* Hq_h  = us + o; o += (size_t)2048*512;
    unsigned short* Hq_l  = us + o; o += (size_t)2048*512;
    unsigned short* Vt_h  = us + o; o += (size_t)2*512*1024;
    unsigned short* Vt_l  = us + o; o += (size_t)2*512*1024;
    unsigned short* CSk_h = us + o; o += (size_t)2048*128;
    unsigned short* CSk_l = us + o; o += (size_t)2048*128;
    unsigned short* CSq_h = us + o; o += (size_t)2048*128;
    unsigned short* CSq_l = us + o; o += (size_t)2048*128;
    unsigned short* Ah    = us + o; o += (size_t)2*1024*1024;
    unsigned short* Al    = us + o; o += (size_t)2*1024*1024;
    float* Rp = (float*)(us + o);   o += (size_t)4 * 2048*512 * 2;

    unsigned* bars = (unsigned*)((char*)d_ws + ws_size - 256);
    (void)hipMemsetAsync(bars, 0, 64, stream);

    mega<<<NBLK, NTHR, 0, stream>>>(
        x, Wk1, bk1, Wk2, bk2, Wq1, bq1, Wq2, bq2, Wv, bv, lng, lnb, Wo, bo,
        out,
        Wt_h, Wt_l, XYh, XYl, Hk_h, Hk_l, Hq_h, Hq_l, Vt_h, Vt_l,
        CSk_h, CSk_l, CSq_h, CSq_l, Ah, Al, Rp, bars);
}

// Round 10
// 168.571 us; speedup vs baseline: 3.4659x; 1.6491x over previous
//
#include <hip/hip_runtime.h>
#include <math.h>

#define L_SEQ 1024
#define M_ROWS 2048
#define PI_F 3.14159265358979323846f

typedef short bf16x8 __attribute__((ext_vector_type(8)));
typedef float f32x4 __attribute__((ext_vector_type(4)));

__device__ __forceinline__ unsigned short bf16_rne(float x) {
    union { float f; unsigned u; } v; v.f = x;
    unsigned r = v.u + 0x7fffu + ((v.u >> 16) & 1u);
    return (unsigned short)(r >> 16);
}
__device__ __forceinline__ float bf16_tof(unsigned short h) {
    union { unsigned u; float f; } v; v.u = ((unsigned)h) << 16;
    return v.f;
}
__device__ __forceinline__ void split2(float x, unsigned short &h, unsigned short &l) {
    h = bf16_rne(x);
    l = bf16_rne(x - bf16_tof(h));
}
__device__ __forceinline__ float gelu_exact(float x) {
    return 0.5f * x * (1.0f + erff(x * 0.70710678118654752f));
}
__device__ __forceinline__ f32x4 mfma16(bf16x8 a, bf16x8 b, f32x4 c) {
    return __builtin_amdgcn_mfma_f32_16x16x32_bf16(a, b, c, 0, 0, 0);
}
__device__ __forceinline__ void gload_lds16(const unsigned short* g, unsigned short* l) {
    __builtin_amdgcn_global_load_lds(
        (const __attribute__((address_space(1))) void*)g,
        (__attribute__((address_space(3))) void*)l, 16, 0, 0);
}

// Stage R x 32 bf16 tile into LDS (row = 64B), pre-swizzled source.
// 512 threads: R=128 uses all 8 waves; R=64 uses waves 0-3.
__device__ __forceinline__ void stage_tile(
    const unsigned short* __restrict__ src, int ld, int rowBase, int k0,
    unsigned short* lds_tile, int R)
{
    const int tid = threadIdx.x;
    if (R == 128 || tid < 256) {
        const int r = tid >> 2;
        const int c = (tid & 3) ^ ((r >> 1) & 3);
        const unsigned short* g = src + (size_t)(rowBase + r) * ld + k0 + c * 8;
        unsigned short* l = lds_tile + (tid >> 6) * 512;   // wave-uniform base
        gload_lds16(g, l);
    }
}

// LDS-staged split-bf16 GEMM core. 512 threads = 8 waves (2m x 4n).
// Block tile = (32*MI) x (64*NI). K-step 32, double-buffered.
template<int MI, int NI>
__device__ __forceinline__ void lds_gemm(
    unsigned short* lds,
    const unsigned short* Ah_, const unsigned short* Al_, int lda, int aRow,
    const unsigned short* Bh_, const unsigned short* Bl_, int ldb, int bRow,
    int k0, int nk, f32x4 (&acc)[MI][NI])
{
    constexpr int RA = MI * 32, RB = NI * 64;
    constexpr int SZA = RA * 32;
    constexpr int SZB = RB * 32;
    constexpr int BUF = 2 * SZA + 2 * SZB;
    const int tid = threadIdx.x, lane = tid & 63;
    const int wm = (tid >> 8) & 1;
    const int wn = (tid >> 6) & 3;

    stage_tile(Ah_, lda, aRow, k0, lds,                 RA);
    stage_tile(Al_, lda, aRow, k0, lds + SZA,           RA);
    stage_tile(Bh_, ldb, bRow, k0, lds + 2 * SZA,       RB);
    stage_tile(Bl_, ldb, bRow, k0, lds + 2 * SZA + SZB, RB);

    for (int ks = 0; ks < nk; ++ks) {
        const int cur = (ks & 1) * BUF;
        const int nxt = ((ks & 1) ^ 1) * BUF;
        __syncthreads();
        if (ks + 1 < nk) {
            const int kk = k0 + (ks + 1) * 32;
            stage_tile(Ah_, lda, aRow, kk, lds + nxt,                 RA);
            stage_tile(Al_, lda, aRow, kk, lds + nxt + SZA,           RA);
            stage_tile(Bh_, ldb, bRow, kk, lds + nxt + 2 * SZA,       RB);
            stage_tile(Bl_, ldb, bRow, kk, lds + nxt + 2 * SZA + SZB, RB);
        }
        const int lr = lane & 15, j = lane >> 4;
        bf16x8 ah[MI], al[MI], bh[NI], bl[NI];
#pragma unroll
        for (int mi = 0; mi < MI; ++mi) {
            const int r = wm * (MI * 16) + mi * 16 + lr;
            const int off = cur + r * 32 + ((j ^ ((r >> 1) & 3)) << 3);
            ah[mi] = *(const bf16x8*)(lds + off);
            al[mi] = *(const bf16x8*)(lds + off + SZA);
        }
#pragma unroll
        for (int ni = 0; ni < NI; ++ni) {
            const int r = wn * (NI * 16) + ni * 16 + lr;
            const int off = cur + 2 * SZA + r * 32 + ((j ^ ((r >> 1) & 3)) << 3);
            bh[ni] = *(const bf16x8*)(lds + off);
            bl[ni] = *(const bf16x8*)(lds + off + SZB);
        }
#pragma unroll
        for (int mi = 0; mi < MI; ++mi)
#pragma unroll
            for (int ni = 0; ni < NI; ++ni) {
                acc[mi][ni] = mfma16(ah[mi], bh[ni], acc[mi][ni]);
                acc[mi][ni] = mfma16(ah[mi], bl[ni], acc[mi][ni]);
                acc[mi][ni] = mfma16(al[mi], bh[ni], acc[mi][ni]);
            }
    }
}

// ---------------------------------------------------------------------------
// prep: W transpose+split (units 0..271) and X split (units 272..527).
// ---------------------------------------------------------------------------
__global__ __launch_bounds__(512) void prep(
    const float* __restrict__ x,
    const float* __restrict__ Wk1, const float* __restrict__ Wq1,
    const float* __restrict__ Wv,  const float* __restrict__ Wo,
    const float* __restrict__ Wk2, const float* __restrict__ Wq2,
    unsigned short* __restrict__ Wt_h, unsigned short* __restrict__ Wt_l,
    unsigned short* __restrict__ XYh,  unsigned short* __restrict__ XYl)
{
    const int u = blockIdx.x;
    const int tid = threadIdx.x;
    if (u < 272) {
        __shared__ float T[64 * 65];
        const int kT = u & 7, ty = u >> 3;
        const float* src; int srcN, dstRowBase, nBase;
        if (ty < 8)       { src = Wk1; srcN = 512; dstRowBase = 0;    nBase = ty * 64; }
        else if (ty < 16) { src = Wq1; srcN = 512; dstRowBase = 512;  nBase = (ty-8)*64; }
        else if (ty < 24) { src = Wv;  srcN = 512; dstRowBase = 1024; nBase = (ty-16)*64; }
        else if (ty < 32) { src = Wo;  srcN = 512; dstRowBase = 1536; nBase = (ty-24)*64; }
        else if (ty == 32){ src = Wk2; srcN = 64;  dstRowBase = 2048; nBase = 0; }
        else              { src = Wq2; srcN = 64;  dstRowBase = 2112; nBase = 0; }
        const int k0 = kT * 64;
        {
            const int r = tid >> 3, c0 = (tid & 7) * 8;
#pragma unroll
            for (int i = 0; i < 2; ++i) {
                float4 v = *reinterpret_cast<const float4*>(
                    src + (size_t)(k0 + r) * srcN + nBase + c0 + i*4);
                T[r*65 + c0+i*4+0] = v.x; T[r*65 + c0+i*4+1] = v.y;
                T[r*65 + c0+i*4+2] = v.z; T[r*65 + c0+i*4+3] = v.w;
            }
        }
        __syncthreads();
        {
            const int n = tid >> 3, kk0 = (tid & 7) * 8;
            const size_t base = (size_t)(dstRowBase + nBase + n) * 512 + k0 + kk0;
#pragma unroll
            for (int i = 0; i < 8; ++i) {
                unsigned short h, l;
                split2(T[(kk0 + i)*65 + n], h, l);
                Wt_h[base + i] = h; Wt_l[base + i] = l;
            }
        }
    } else {
        const int xb = u - 272;   // 0..255
#pragma unroll
        for (int ii = 0; ii < 2; ++ii) {
            const size_t i = (size_t)xb * 1024 + ii * 512 + tid;
            float4 v = reinterpret_cast<const float4*>(x)[i];
            unsigned short h0,h1,h2,h3,l0,l1,l2,l3;
            split2(v.x,h0,l0); split2(v.y,h1,l1); split2(v.z,h2,l2); split2(v.w,h3,l3);
            unsigned long long hp = (unsigned long long)h0 | ((unsigned long long)h1<<16)
                                  | ((unsigned long long)h2<<32) | ((unsigned long long)h3<<48);
            unsigned long long lp = (unsigned long long)l0 | ((unsigned long long)l1<<16)
                                  | ((unsigned long long)l2<<32) | ((unsigned long long)l3<<48);
            reinterpret_cast<unsigned long long*>(XYh)[i] = hp;
            reinterpret_cast<unsigned long long*>(XYl)[i] = lp;
        }
    }
}

// ---------------------------------------------------------------------------
// qkv: 192 units of 128x128; gelu on k/q segs, V transposed per batch.
// ---------------------------------------------------------------------------
__global__ __launch_bounds__(512) void qkv_mfma(
    const unsigned short* __restrict__ XYh, const unsigned short* __restrict__ XYl,
    const unsigned short* __restrict__ Wt_h, const unsigned short* __restrict__ Wt_l,
    const float* __restrict__ bk1, const float* __restrict__ bq1, const float* __restrict__ bv,
    unsigned short* __restrict__ Hk_h, unsigned short* __restrict__ Hk_l,
    unsigned short* __restrict__ Hq_h, unsigned short* __restrict__ Hq_l,
    unsigned short* __restrict__ Vt_h, unsigned short* __restrict__ Vt_l)
{
    __shared__ __align__(16) unsigned short lds[32768];   // 64KB for <4,2>
    const int tid = threadIdx.x, lane = tid & 63;
    const int nT = blockIdx.x % 12, mT = blockIdx.x / 12;
    const int mBase = mT * 128, nBase = nT * 128;
    const int wm = (tid >> 8) & 1, wn = (tid >> 6) & 3;
    f32x4 acc[4][2];
#pragma unroll
    for (int i = 0; i < 4; ++i)
#pragma unroll
        for (int jj = 0; jj < 2; ++jj) acc[i][jj] = (f32x4){0.f,0.f,0.f,0.f};
    lds_gemm<4,2>(lds, XYh, XYl, 512, mBase, Wt_h, Wt_l, 512, nBase, 0, 16, acc);
    const int seg = nBase >> 9;
    const float* bias = (seg == 0) ? bk1 : (seg == 1) ? bq1 : bv;
#pragma unroll
    for (int mi = 0; mi < 4; ++mi)
#pragma unroll
    for (int ni = 0; ni < 2; ++ni)
#pragma unroll
    for (int r = 0; r < 4; ++r) {
        const int row = mBase + wm*64 + mi*16 + (lane>>4)*4 + r;
        const int col = nBase + wn*32 + ni*16 + (lane&15);
        const int nW = col & 511;
        float v = acc[mi][ni][r] + bias[nW];
        if (seg < 2) v = gelu_exact(v);
        unsigned short h, l;
        split2(v, h, l);
        if (seg == 0)      { Hk_h[(size_t)row*512 + nW] = h; Hk_l[(size_t)row*512 + nW] = l; }
        else if (seg == 1) { Hq_h[(size_t)row*512 + nW] = h; Hq_l[(size_t)row*512 + nW] = l; }
        else {
            const size_t o = (size_t)((row >> 10)*512 + nW) * 1024 + (row & 1023);
            Vt_h[o] = h; Vt_l[o] = l;
        }
    }
}

// ---------------------------------------------------------------------------
// phase heads: 64 units of 64 rows; p = tanh(H@W2+b2)*pi -> [cos|sin] hi/lo.
// ---------------------------------------------------------------------------
__global__ __launch_bounds__(512) void phase_mfma(
    const unsigned short* __restrict__ Hk_h, const unsigned short* __restrict__ Hk_l,
    const unsigned short* __restrict__ Hq_h, const unsigned short* __restrict__ Hq_l,
    const unsigned short* __restrict__ Wt_h, const unsigned short* __restrict__ Wt_l,
    const float* __restrict__ bk2, const float* __restrict__ bq2,
    unsigned short* __restrict__ CSk_h, unsigned short* __restrict__ CSk_l,
    unsigned short* __restrict__ CSq_h, unsigned short* __restrict__ CSq_l)
{
    __shared__ __align__(16) unsigned short lds[16384];   // 32KB for <2,1>
    const int tid = threadIdx.x, lane = tid & 63;
    const int enc = blockIdx.x & 1, mT = blockIdx.x >> 1;
    const unsigned short* Ah_ = enc ? Hq_h : Hk_h;
    const unsigned short* Al_ = enc ? Hq_l : Hk_l;
    const float* b2 = enc ? bq2 : bk2;
    unsigned short* Ch = enc ? CSq_h : CSk_h;
    unsigned short* Cl = enc ? CSq_l : CSk_l;
    const int wm = (tid >> 8) & 1, wn = (tid >> 6) & 3;
    f32x4 acc[2][1];
#pragma unroll
    for (int i = 0; i < 2; ++i) acc[i][0] = (f32x4){0.f,0.f,0.f,0.f};
    lds_gemm<2,1>(lds, Ah_, Al_, 512, mT*64, Wt_h, Wt_l, 512, 2048 + enc*64, 0, 16, acc);
#pragma unroll
    for (int mi = 0; mi < 2; ++mi)
#pragma unroll
    for (int r = 0; r < 4; ++r) {
        const int row = mT*64 + wm*32 + mi*16 + (lane>>4)*4 + r;
        const int j = wn*16 + (lane&15);
        float p = acc[mi][0][r] + b2[j];
        p = tanhf(p) * PI_F;
        float s, c;
        sincosf(p, &s, &c);
        unsigned short h, l;
        split2(c, h, l);
        Ch[(size_t)row*128 + j] = h; Cl[(size_t)row*128 + j] = l;
        split2(s, h, l);
        Ch[(size_t)row*128 + 64 + j] = h; Cl[(size_t)row*128 + 64 + j] = l;
    }
}

// ---------------------------------------------------------------------------
// scores: 256 units (64 t-rows x 128 s-cols), lower-tri; upper zeroed.
// ---------------------------------------------------------------------------
__global__ __launch_bounds__(512) void scores_mfma(
    const unsigned short* __restrict__ CSq_h, const unsigned short* __restrict__ CSq_l,
    const unsigned short* __restrict__ CSk_h, const unsigned short* __restrict__ CSk_l,
    unsigned short* __restrict__ Ah, unsigned short* __restrict__ Al)
{
    const int u = blockIdx.x;
    const int b = u >> 7, tT = (u >> 3) & 15, sT = u & 7;
    if (sT * 128 > tT * 64 + 63) return;
    __shared__ __align__(16) unsigned short lds[24576];   // 48KB for <2,2>
    const int tid = threadIdx.x, lane = tid & 63;
    const int wm = (tid >> 8) & 1, wn = (tid >> 6) & 3;
    f32x4 acc[2][2];
#pragma unroll
    for (int i = 0; i < 2; ++i)
#pragma unroll
        for (int jj = 0; jj < 2; ++jj) acc[i][jj] = (f32x4){0.f,0.f,0.f,0.f};
    lds_gemm<2,2>(lds, CSq_h, CSq_l, 128, b*1024 + tT*64,
                  CSk_h, CSk_l, 128, b*1024 + sT*128, 0, 4, acc);
#pragma unroll
    for (int mi = 0; mi < 2; ++mi)
#pragma unroll
    for (int ni = 0; ni < 2; ++ni)
#pragma unroll
    for (int r = 0; r < 4; ++r) {
        const int t = tT*64 + wm*32 + mi*16 + (lane>>4)*4 + r;
        const int s = sT*128 + wn*32 + ni*16 + (lane&15);
        float v = (s <= t) ? acc[mi][ni][r] : 0.f;
        unsigned short h, l;
        split2(v, h, l);
        const size_t o = ((size_t)b*1024 + t) * 1024 + s;
        Ah[o] = h; Al[o] = l;
    }
}

// ---------------------------------------------------------------------------
// av: 512 units (s-chunks of 256 -> partials Rp[c]); 48KB LDS -> 2 blocks/CU.
// ---------------------------------------------------------------------------
__global__ __launch_bounds__(512) void av_mfma(
    const unsigned short* __restrict__ Ah, const unsigned short* __restrict__ Al,
    const unsigned short* __restrict__ Vt_h, const unsigned short* __restrict__ Vt_l,
    float* __restrict__ Rp)
{
    const int u = blockIdx.x;
    const int c = u >> 7, b = (u >> 6) & 1, dT = (u >> 4) & 3, tT = u & 15;
    if (c * 256 > tT * 64 + 63) return;
    __shared__ __align__(16) unsigned short lds[24576];   // 48KB for <2,2>
    const int tid = threadIdx.x, lane = tid & 63;
    const int wm = (tid >> 8) & 1, wn = (tid >> 6) & 3;
    const int kLen = min(256, tT*64 + 64 - c*256);
    const int nk = kLen >> 5;
    f32x4 acc[2][2];
#pragma unroll
    for (int i = 0; i < 2; ++i)
#pragma unroll
        for (int jj = 0; jj < 2; ++jj) acc[i][jj] = (f32x4){0.f,0.f,0.f,0.f};
    lds_gemm<2,2>(lds, Ah, Al, 1024, b*1024 + tT*64,
                  Vt_h, Vt_l, 1024, b*512 + dT*128, c*256, nk, acc);
    float* Rb = Rp + (size_t)c * (M_ROWS * 512);
#pragma unroll
    for (int mi = 0; mi < 2; ++mi)
#pragma unroll
    for (int ni = 0; ni < 2; ++ni)
#pragma unroll
    for (int r = 0; r < 4; ++r) {
        const int row = b*1024 + tT*64 + wm*32 + mi*16 + (lane>>4)*4 + r;
        const int d = dT*128 + wn*32 + ni*16 + (lane&15);
        Rb[(size_t)row*512 + d] = acc[mi][ni][r];
    }
}

// ---------------------------------------------------------------------------
// ln: 256 blocks x 8 rows; LN((sum_c Rp)/sqrt((t+1)K))*g + b -> Y hi/lo.
// ---------------------------------------------------------------------------
__global__ __launch_bounds__(512) void ln_kernel(
    const float* __restrict__ Rp, const float* __restrict__ g,
    const float* __restrict__ bb,
    unsigned short* __restrict__ Yh, unsigned short* __restrict__ Yl)
{
    __shared__ float fbuf[16];
    const int tid = threadIdx.x;
    const int lane = tid & 63, wid = tid >> 6;
    for (int i = 0; i < 8; ++i) {
        const int row = blockIdx.x * 8 + i;
        const int t = row & (L_SEQ - 1);
        const int nc = (t >> 8) + 1;
        const float scale = rsqrtf((float)(t + 1) * 64.0f);
        float v = 0.f;
        for (int c = 0; c < nc; ++c)
            v += Rp[(size_t)c * (M_ROWS * 512) + (size_t)row * 512 + tid];
        v *= scale;
        float s = v, q = v * v;
#pragma unroll
        for (int off = 32; off >= 1; off >>= 1) {
            s += __shfl_down(s, off);
            q += __shfl_down(q, off);
        }
        if (lane == 0) { fbuf[wid] = s; fbuf[8 + wid] = q; }
        __syncthreads();
        float S = 0.f, Q = 0.f;
#pragma unroll
        for (int w = 0; w < 8; ++w) { S += fbuf[w]; Q += fbuf[8 + w]; }
        const float mu  = S * (1.f / 512.f);
        const float var = Q * (1.f / 512.f) - mu * mu;
        const float rr = rsqrtf(var + 1e-5f);
        const float y = (v - mu) * rr * g[tid] + bb[tid];
        unsigned short h, l;
        split2(y, h, l);
        Yh[(size_t)row*512 + tid] = h;
        Yl[(size_t)row*512 + tid] = l;
        __syncthreads();
    }
}

// ---------------------------------------------------------------------------
// out: 128 units of 128x64; out = x + Y @ Wo + bo.
// ---------------------------------------------------------------------------
__global__ __launch_bounds__(512) void out_mfma(
    const unsigned short* __restrict__ Yh, const unsigned short* __restrict__ Yl,
    const unsigned short* __restrict__ Wt_h, const unsigned short* __restrict__ Wt_l,
    const float* __restrict__ bo, const float* __restrict__ x,
    float* __restrict__ out)
{
    __shared__ __align__(16) unsigned short lds[24576];   // 48KB for <4,1>
    const int tid = threadIdx.x, lane = tid & 63;
    const int mT = blockIdx.x >> 3, nT = blockIdx.x & 7;
    const int mBase = mT * 128;
    const int wm = (tid >> 8) & 1, wn = (tid >> 6) & 3;
    f32x4 acc[4][1];
#pragma unroll
    for (int i = 0; i < 4; ++i) acc[i][0] = (f32x4){0.f,0.f,0.f,0.f};
    lds_gemm<4,1>(lds, Yh, Yl, 512, mBase, Wt_h, Wt_l, 512, 1536 + nT*64, 0, 16, acc);
#pragma unroll
    for (int mi = 0; mi < 4; ++mi)
#pragma unroll
    for (int r = 0; r < 4; ++r) {
        const int row = mBase + wm*64 + mi*16 + (lane>>4)*4 + r;
        const int col = nT*64 + wn*16 + (lane&15);
        out[(size_t)row*512 + col] =
            acc[mi][0][r] + bo[col] + x[(size_t)row*512 + col];
    }
}

// ---------------------------------------------------------------------------
extern "C" void kernel_launch(void* const* d_in, const int* in_sizes, int n_in,
                              void* d_out, int out_size, void* d_ws, size_t ws_size,
                              hipStream_t stream)
{
    const float* x   = (const float*)d_in[0];
    const float* Wk1 = (const float*)d_in[1];
    const float* bk1 = (const float*)d_in[2];
    const float* Wk2 = (const float*)d_in[3];
    const float* bk2 = (const float*)d_in[4];
    const float* Wq1 = (const float*)d_in[5];
    const float* bq1 = (const float*)d_in[6];
    const float* Wq2 = (const float*)d_in[7];
    const float* bq2 = (const float*)d_in[8];
    const float* Wv  = (const float*)d_in[9];
    const float* bv  = (const float*)d_in[10];
    const float* lng = (const float*)d_in[11];
    const float* lnb = (const float*)d_in[12];
    const float* Wo  = (const float*)d_in[13];
    const float* bo  = (const float*)d_in[14];
    float* out = (float*)d_out;

    unsigned short* us = (unsigned short*)d_ws;
    size_t o = 0;
    unsigned short* Wt_h  = us + o; o += (size_t)2176*512;
    unsigned short* Wt_l  = us + o; o += (size_t)2176*512;
    unsigned short* XYh   = us + o; o += (size_t)2048*512;
    unsigned short* XYl   = us + o; o += (size_t)2048*512;
    unsigned short* Hk_h  = us + o; o += (size_t)2048*512;
    unsigned short* Hk_l  = us + o; o += (size_t)2048*512;
    unsigned short* Hq_h  = us + o; o += (size_t)2048*512;
    unsigned short* Hq_l  = us + o; o += (size_t)2048*512;
    unsigned short* Vt_h  = us + o; o += (size_t)2*512*1024;
    unsigned short* Vt_l  = us + o; o += (size_t)2*512*1024;
    unsigned short* CSk_h = us + o; o += (size_t)2048*128;
    unsigned short* CSk_l = us + o; o += (size_t)2048*128;
    unsigned short* CSq_h = us + o; o += (size_t)2048*128;
    unsigned short* CSq_l = us + o; o += (size_t)2048*128;
    unsigned short* Ah    = us + o; o += (size_t)2*1024*1024;
    unsigned short* Al    = us + o; o += (size_t)2*1024*1024;
    float* Rp = (float*)(us + o);   o += (size_t)4 * 2048*512 * 2;

    prep<<<528, 512, 0, stream>>>(x, Wk1, Wq1, Wv, Wo, Wk2, Wq2,
                                  Wt_h, Wt_l, XYh, XYl);
    qkv_mfma<<<192, 512, 0, stream>>>(XYh, XYl, Wt_h, Wt_l, bk1, bq1, bv,
                                      Hk_h, Hk_l, Hq_h, Hq_l, Vt_h, Vt_l);
    phase_mfma<<<64, 512, 0, stream>>>(Hk_h, Hk_l, Hq_h, Hq_l, Wt_h, Wt_l,
                                       bk2, bq2, CSk_h, CSk_l, CSq_h, CSq_l);
    scores_mfma<<<256, 512, 0, stream>>>(CSq_h, CSq_l, CSk_h, CSk_l, Ah, Al);
    av_mfma<<<512, 512, 0, stream>>>(Ah, Al, Vt_h, Vt_l, Rp);
    ln_kernel<<<256, 512, 0, stream>>>(Rp, lng, lnb, XYh, XYl);
    out_mfma<<<128, 512, 0, stream>>>(XYh, XYl, Wt_h, Wt_l, bo, x, out);
}